// Round 8
// baseline (314.202 us; speedup 1.0000x reference)
//
#include <hip/hip_runtime.h>
#include <math.h>

#ifndef M_PI
#define M_PI 3.14159265358979323846
#endif

#define NSAMP 32768
#define MHALF 16384
#define TWO_PI_F 6.2831853071795864f
#define PSTRIDE 1089   // plane stride in v2; 1089&15==1 spreads planes across bank pairs

typedef float v2 __attribute__((ext_vector_type(2)));

__device__ __forceinline__ double dsig(double x) { return 1.0 / (1.0 + exp(-x)); }

// ---------------------------------------------------------------------------
// Complex helpers on packed 2-float vectors
// ---------------------------------------------------------------------------
__device__ __forceinline__ v2 cmul(v2 a, v2 b) {
    return a.xx * b + (v2){-a.y, a.y} * b.yx;
}

template<int INV>
__device__ __forceinline__ void fft4(v2& x0, v2& x1, v2& x2, v2& x3) {
    v2 s02 = x0 + x2;
    v2 d02 = x0 - x2;
    v2 s13 = x1 + x3;
    v2 d13 = x1 - x3;
    v2 j13 = INV ? (v2){-d13.y, d13.x} : (v2){d13.y, -d13.x};
    x0 = s02 + s13;
    x2 = s02 - s13;
    x1 = d02 + j13;
    x3 = d02 - j13;
}

// After fft16, natural-order output index c lives in register V16(v,c).
#define V16(v, c) v[((((c) & 3) << 2) | ((c) >> 2))]

template<int INV>
__device__ __forceinline__ void fft16(v2 v[16]) {
    const float s = INV ? 1.0f : -1.0f;
#pragma unroll
    for (int b = 0; b < 4; b++) fft4<INV>(v[b], v[4 + b], v[8 + b], v[12 + b]);
    v[5]  = cmul(v[5],  (v2){0.9238795325f,  s * 0.3826834324f});
    v[9]  = cmul(v[9],  (v2){0.7071067812f,  s * 0.7071067812f});
    v[13] = cmul(v[13], (v2){0.3826834324f,  s * 0.9238795325f});
    v[6]  = cmul(v[6],  (v2){0.7071067812f,  s * 0.7071067812f});
    v[10] = cmul(v[10], (v2){0.0f,           s * 1.0f});
    v[14] = cmul(v[14], (v2){-0.7071067812f, s * 0.7071067812f});
    v[7]  = cmul(v[7],  (v2){0.3826834324f,  s * 0.9238795325f});
    v[11] = cmul(v[11], (v2){-0.7071067812f, s * 0.7071067812f});
    v[15] = cmul(v[15], (v2){-0.9238795325f, s * -0.3826834324f});
#pragma unroll
    for (int p = 0; p < 4; p++) fft4<INV>(v[4 * p], v[4 * p + 1], v[4 * p + 2], v[4 * p + 3]);
}

// spectral k (0..16383) -> LDS index.
__device__ __forceinline__ int zaddr(int k) {
    int p = k & 15, k2 = k >> 4;
    int s = 256 * (k2 & 3) + 16 * ((k2 >> 2) & 15) + (k2 >> 6);
    return p * PSTRIDE + s + (s >> 4);
}

// forward wave-local 1024-pt FFT on plane (lane l).
__device__ __forceinline__ void plane_fwd(v2* __restrict__ Zp, int l) {
    {
        float sn, cs;
        __sincosf(TWO_PI_F * (float)l * (1.f / 1024.f), &sn, &cs);
        v2 w1 = (v2){cs, -sn};
        const v2 jstep = (v2){0.9238795325f, -0.3826834324f}; // e^{-2pi i/16}
#pragma unroll
        for (int j = 0; j < 4; j++) {
            const int r = 64 * j + l;
            v2 u0 = Zp[r], u1 = Zp[256 + r], u2 = Zp[512 + r], u3 = Zp[768 + r];
            fft4<0>(u0, u1, u2, u3);
            v2 w2 = cmul(w1, w1);
            v2 w3 = cmul(w2, w1);
            Zp[r] = u0;
            Zp[256 + r] = cmul(u1, w1);
            Zp[512 + r] = cmul(u2, w2);
            Zp[768 + r] = cmul(u3, w3);
            w1 = cmul(w1, jstep);
        }
    }
    {
        const int k4 = l >> 4, c = l & 15;
        const int nbase = 256 * k4 + c;
        float sn, cs;
        __sincosf(TWO_PI_F * (float)c * (1.f / 256.f), &sn, &cs);
        const v2 wc = (v2){cs, -sn};
        v2 v[16];
#pragma unroll
        for (int b = 0; b < 16; b++) v[b] = Zp[nbase + 16 * b];
        fft16<0>(v);
        const int pbase = 272 * k4 + c;
        Zp[pbase] = V16(v, 0);
        v2 w = wc;
#pragma unroll
        for (int kb = 1; kb < 16; kb++) {
            Zp[pbase + 17 * kb] = cmul(V16(v, kb), w);
            w = cmul(w, wc);
        }
    }
    {
        const int pbase = 272 * (l >> 4) + 17 * (l & 15);
        v2 v[16];
#pragma unroll
        for (int c = 0; c < 16; c++) v[c] = Zp[pbase + c];
        fft16<0>(v);
#pragma unroll
        for (int kc = 0; kc < 16; kc++) Zp[pbase + kc] = V16(v, kc);
    }
}

// inverse wave-local 1024-pt FFT (mirror order, conjugate twiddles).
__device__ __forceinline__ void plane_inv(v2* __restrict__ Zp, int l) {
    {
        const int kb = l & 15;
        const int pbase = 272 * (l >> 4) + 17 * kb;
        float sn, cs;
        __sincosf(TWO_PI_F * (float)kb * (1.f / 256.f), &sn, &cs);
        const v2 wkb = (v2){cs, sn};
        v2 v[16];
#pragma unroll
        for (int kc = 0; kc < 16; kc++) v[kc] = Zp[pbase + kc];
        fft16<1>(v);
        Zp[pbase] = V16(v, 0);
        v2 w = wkb;
#pragma unroll
        for (int nc = 1; nc < 16; nc++) {
            Zp[pbase + nc] = cmul(V16(v, nc), w);
            w = cmul(w, wkb);
        }
    }
    {
        const int k4 = l >> 4, nc = l & 15;
        const int pbase = 272 * k4 + nc;
        float sni, csi;
        __sincosf(TWO_PI_F * (float)(nc * k4) * (1.f / 1024.f), &sni, &csi);
        v2 t = (v2){csi, sni};
        float sns, css;
        __sincosf(TWO_PI_F * (float)k4 * (1.f / 64.f), &sns, &css);
        const v2 st = (v2){css, sns};
        v2 v[16];
#pragma unroll
        for (int kb = 0; kb < 16; kb++) v[kb] = Zp[pbase + 17 * kb];
        fft16<1>(v);
#pragma unroll
        for (int nb = 0; nb < 16; nb++) {
            Zp[pbase + 17 * nb] = cmul(V16(v, nb), t);
            t = cmul(t, st);
        }
    }
#pragma unroll
    for (int j = 0; j < 4; j++) {
        const int r = 64 * j + l;
        const int rp = r + (r >> 4);
        v2 u0 = Zp[rp], u1 = Zp[272 + rp], u2 = Zp[544 + rp], u3 = Zp[816 + rp];
        fft4<1>(u0, u1, u2, u3);
        Zp[rp] = u0; Zp[272 + rp] = u1; Zp[544 + rp] = u2; Zp[816 + rp] = u3;
    }
}

__device__ __forceinline__ float hinterp64(const float* f, int j) {
    float pos = ((float)j + 0.5f) * (1.0f / 256.0f) - 0.5f;
    pos = fminf(fmaxf(pos, 0.0f), 63.0f);
    int lo = (int)pos;
    int hi = min(lo + 1, 63);
    float w = pos - (float)lo;
    return f[lo] * (1.0f - w) + f[hi] * w;
}

// ---------------------------------------------------------------------------
// Sine synthesis, event E of this block's group, at the block's 4 samples.
// FULLY SELF-CONTAINED (round-5 discipline): interpolation coefficients and
// window indices are recomputed inside every call (~25 VALU) so NOTHING
// call-local is live across FFT phases. The only persistent state is the
// caller's float4 acc (4 VGPRs). Round 7 kept coeffs/indices persistent ->
// compiler demoted them to scratch at its 64-VGPR ceiling -> 700 MB of
// spill traffic. Do not reintroduce persistent arrays.
// ---------------------------------------------------------------------------
template<int E>
__device__ __forceinline__ void synth_event(
    int tid, int echunk, const float* __restrict__ envg,
    const unsigned long long* __restrict__ stepg, float4& acc)
{
    const int s0 = (echunk << 12) + (tid << 2);

    float c0v[4], c1v[4], c2v[4];
    float pos0 = ((float)s0 + 0.5f) * (1.0f / 256.0f) - 0.5f;
    pos0 = fminf(fmaxf(pos0, 0.0f), 127.0f);
    const int lo0 = (int)pos0;
#pragma unroll
    for (int k = 0; k < 4; k++) {
        float pos = ((float)(s0 + k) + 0.5f) * (1.0f / 256.0f) - 0.5f;
        pos = fminf(fmaxf(pos, 0.0f), 127.0f);
        int lo = (int)pos;
        float w = pos - (float)lo;
        if (lo == lo0) { c0v[k] = 1.0f - w; c1v[k] = w;        c2v[k] = 0.0f; }
        else           { c0v[k] = 0.0f;     c1v[k] = 1.0f - w; c2v[k] = w;    }
    }
    const int i1 = min(lo0 + 1, 127);
    float pos3 = ((float)(s0 + 3) + 0.5f) * (1.0f / 256.0f) - 0.5f;
    pos3 = fminf(fmaxf(pos3, 0.0f), 127.0f);
    const int i2 = min((int)pos3 + 1, 127);

    const int wbase = max(0, echunk * 16 - 1);
    const int j0 = lo0 - wbase, j1 = i1 - wbase, j2 = i2 - wbase;

    float v0a[8], v1a[8], v2a[8];
    const float* er = envg + E * (8 * 18);
#pragma unroll
    for (int h = 0; h < 8; h++) {
        v0a[h] = er[h * 18 + j0];
        v1a[h] = er[h * 18 + j1];
        v2a[h] = er[h * 18 + j2];
    }

    const unsigned long long st1 = stepg[E];
    const float stf1 = (float)(unsigned)(st1 >> 32) * 0x1p-32f;
    const unsigned long long pp = st1 * (unsigned long long)(unsigned)(s0 + 1);
    float fr = (float)(unsigned)(pp >> 32) * 0x1p-32f;

    float out[4];
#pragma unroll
    for (int k = 0; k < 4; k++) {
        const float sn = __builtin_amdgcn_sinf(fr);
        const float cs = __builtin_amdgcn_cosf(fr);
        const float c2 = cs + cs;
        float s_prev = 0.0f, s_cur = sn, a = 0.0f;
#pragma unroll
        for (int h = 0; h < 8; h++) {
            const float ev = fmaf(v0a[h], c0v[k], fmaf(v1a[h], c1v[k], v2a[h] * c2v[k]));
            a = fmaf(ev, s_cur, a);
            const float s_next = fmaf(c2, s_cur, -s_prev);
            s_prev = s_cur; s_cur = s_next;
        }
        out[k] = a;
        fr = __builtin_amdgcn_fractf(fr + stf1);
    }
    acc.x += out[0]; acc.y += out[1]; acc.z += out[2]; acc.w += out[3];
}

// ---------------------------------------------------------------------------
// Fused kernel (round-5 skeleton + final-sine partitioning):
//   block (g,e): FFT-filters event g*8+e (filt partial, 32 MB total), AND
//   synthesizes chunk e (4096 samples) of the group's COMPLETE sine sum,
//   interleaved into the FFT stall slots. Sine result is FINAL -> out (4 MB).
// Prep: waves 0-7 handle the group's 8 events, publishing the chunk-window
// envelope envg[8][8][18] + fundamental steps to LDS (validated round 7).
// ---------------------------------------------------------------------------
__global__ __launch_bounds__(1024)
__attribute__((amdgpu_waves_per_eu(4, 4)))
void fused_kernel(
    const float* __restrict__ packed, const float* __restrict__ freqs,
    const float* __restrict__ noise, float* __restrict__ part,
    float* __restrict__ out)
{
    __shared__ v2 Z[16 * PSTRIDE];       // 139,392 B
    __shared__ float fenv_s[64];
    __shared__ float amp_s[128];
    __shared__ float envg[8][8][18];     // group envelopes, chunk window (4,608 B)
    __shared__ unsigned long long stepg[8];  // group fundamental steps

    const int bid = blockIdx.x;
    const int g = (bid & 7) + 8 * ((bid >> 3) & 3);   // group 0..31; bid%8 == g%8 (XCD affinity)
    const int echunk = bid >> 5;                      // event slot == sine chunk 0..7
    const int bb = g * 8 + echunk;                    // this block's FFT event
    const int tid = threadIdx.x;
    const int wv = tid >> 6, l = tid & 63;

    // ---- prep: waves 0..7, wave w handles group event w
    if (wv < 8) {
        const int ev = g * 8 + wv;
        const float* pk = packed + ev * 464;
        double e0 = exp(dsig((double)pk[l]));
        double e1 = exp(dsig((double)pk[l + 64]));
        double num = e0 * (double)freqs[l] + e1 * (double)freqs[l + 64];
        double den = e0 + e1;
#pragma unroll
        for (int off = 32; off > 0; off >>= 1) {
            num += __shfl_down(num, off);
            den += __shfl_down(den, off);
        }
        num = __shfl(num, 0);
        den = __shfl(den, 0);

        float a0 = (float)(dsig((double)pk[256 + l]) * 2.0 - 1.0);
        float a1 = (float)(dsig((double)pk[256 + 64 + l]) * 2.0 - 1.0);
        if (wv == echunk) {
            amp_s[l] = a0; amp_s[l + 64] = a1;
            fenv_s[l] = (float)dsig((double)pk[400 + l]);
        }

        if (l == 0) {
            const double NYQ = 11025.0;
            const double MIN_F0 = 40.0 / NYQ;
            const double MAX_F0 = 3000.0 / NYQ;
            const double F0_SPAN = MAX_F0 - MIN_F0;
            double f0 = num / den;
            double G = MIN_F0 + f0 * NYQ * F0_SPAN;
            double r = G / NYQ * M_PI;             // fundamental (factor 1)
            double rv = r / (2.0 * M_PI);
            rv -= floor(rv);
            stepg[wv] = (unsigned long long)(rv * 18446744073709551616.0);
        }

        // env recurrence: lanes 0-7 store harmonics; all 64 lanes stay active
        // so the amp shfl sources are valid. Only the ~18 frames this block's
        // chunk interpolates are stored.
        const int wbase = max(0, echunk * 16 - 1);
        const int hh = l & 7;
        float ha = (float)dsig((double)pk[384 + hh]);
        float hd = 0.9f + (float)dsig((double)pk[392 + hh]) * 0.1f;
        float cur = 0.0f;
        for (int fr = 0; fr < 128; fr++) {
            const float af = __shfl(fr < 64 ? a0 : a1, fr & 63);
            cur = fmaf(af, ha, cur);
            cur = fminf(fmaxf(cur, 0.0f), 1.0f);
            if (l < 8 && fr >= wbase && fr < wbase + 18) envg[wv][l][fr - wbase] = cur;
            cur *= hd;
        }
    }

    float4 acc = make_float4(0.f, 0.f, 0.f, 0.f);   // ONLY persistent synth state

    const v2* nz = (const v2*)(noise + (size_t)bb * NSAMP);

    // ---- forward outer: in-thread fft16 over n1 (stride 1024), scatter to planes
    {
        v2 v[16];
#pragma unroll
        for (int a = 0; a < 16; a++) {
            v2 t = nz[a * 1024 + tid];
            v[a] = t * 2.f - 1.f;
        }
        fft16<0>(v);
        float sn, cs;
        __sincosf(TWO_PI_F * (float)tid * (1.f / 16384.f), &sn, &cs);
        const v2 ws = (v2){cs, -sn};
        Z[tid] = V16(v, 0);
        v2 w = ws;
#pragma unroll
        for (int k1 = 1; k1 < 16; k1++) {
            Z[k1 * PSTRIDE + tid] = cmul(V16(v, k1), w);
            w = cmul(w, ws);
        }
    }
    __syncthreads();   // B1: prep + scatter visible

    synth_event<0>(tid, echunk, &envg[0][0][0], stepg, acc);
    synth_event<1>(tid, echunk, &envg[0][0][0], stepg, acc);

    plane_fwd(Z + wv * PSTRIDE, l);     // wave-local, no barriers

    synth_event<2>(tid, echunk, &envg[0][0][0], stepg, acc);
    synth_event<3>(tid, echunk, &envg[0][0][0], stepg, acc);
    __syncthreads();   // B2

    // ---- spectral combine (recurrence twiddles)
    const float invM = 1.0f / (float)MHALF;
    {
        float sn0, cs0;
        __sincosf((float)M_PI * (float)tid * (1.f / 16384.f), &sn0, &cs0);
        v2 t = (v2){cs0, sn0};
        const v2 tstep = (v2){0.98078528040323f, 0.19509032201613f}; // e^{+i pi/16}
        for (int k = tid; k <= 8192; k += 1024) {
            if (k == 0) {
                int i0 = zaddr(0);
                v2 Z0 = Z[i0];
                float Y0 = (Z0.x + Z0.y) * hinterp64(fenv_s, 0);
                float vv = Y0 * 0.5f * invM;
                Z[i0] = (v2){vv, vv};
            } else if (k == 8192) {
                int i8 = zaddr(8192);
                float s = hinterp64(fenv_s, 8192) * invM;
                Z[i8] = Z[i8] * s;
            } else {
                int ik = zaddr(k), imk = zaddr(16384 - k);
                v2 Zk = Z[ik], Zm = Z[imk];
                float Ex = 0.5f * (Zk.x + Zm.x);
                float Ey = 0.5f * (Zk.y - Zm.y);
                float Ox = 0.5f * (Zk.y + Zm.y);
                float Oy = -0.5f * (Zk.x - Zm.x);
                float cs = t.x, sn = t.y;
                float Xkx = Ex + cs * Ox + sn * Oy;
                float Xky = Ey + cs * Oy - sn * Ox;
                float Xmx = Ex - cs * Ox - sn * Oy;
                float Xmy = -Ey + cs * Oy - sn * Ox;
                float Hk = hinterp64(fenv_s, k);
                float Hm = hinterp64(fenv_s, 16384 - k);
                float Ykx = Xkx * Hk, Yky = Xky * Hk;
                float Ymx = Xmx * Hm, Ymy = Xmy * Hm;
                float Er = 0.5f * (Ykx + Ymx);
                float Ei = 0.5f * (Yky - Ymy);
                float Pr = 0.5f * (Ykx - Ymx);
                float Pi = 0.5f * (Yky + Ymy);
                float Oyx = Pr * cs - Pi * sn;
                float Oyy = Pr * sn + Pi * cs;
                Z[ik]  = (v2){(Er - Oyy) * invM, (Ei + Oyx) * invM};
                Z[imk] = (v2){(Er + Oyy) * invM, (-Ei + Oyx) * invM};
            }
            t = cmul(t, tstep);
        }
    }

    synth_event<4>(tid, echunk, &envg[0][0][0], stepg, acc);
    synth_event<5>(tid, echunk, &envg[0][0][0], stepg, acc);
    __syncthreads();   // B3

    plane_inv(Z + wv * PSTRIDE, l);     // wave-local, no barriers

    synth_event<6>(tid, echunk, &envg[0][0][0], stepg, acc);
    synth_event<7>(tid, echunk, &envg[0][0][0], stepg, acc);

    // sine sum is FINAL for these samples -> straight to out
    *(float4*)(out + ((size_t)g << 15) + ((echunk << 12) + (tid << 2))) = acc;
    __syncthreads();   // B4

    // ---- inverse outer: gather across planes, twiddle, fft16, amp,
    //      store 8*filt*amp partial (coalesced v2)
    {
        const int tp = tid + (tid >> 4);
        v2 v[16];
#pragma unroll
        for (int k1 = 0; k1 < 16; k1++) v[k1] = Z[k1 * PSTRIDE + tp];
        float sn, cs;
        __sincosf(TWO_PI_F * (float)tid * (1.f / 16384.f), &sn, &cs);
        const v2 wg = (v2){cs, sn};
        v2 w = wg;
#pragma unroll
        for (int k1 = 1; k1 < 16; k1++) {
            v[k1] = cmul(v[k1], w);
            w = cmul(w, wg);
        }
        fft16<1>(v);

        v2* fo = (v2*)(part + ((size_t)bb << 15));
#pragma unroll
        for (int m = 0; m < 16; m++) {
            v2 y = V16(v, m);
            int A = m * 1024 + tid;
            int s0 = 2 * A;
            float p0 = ((float)s0 + 0.5f) * (1.0f / 256.0f) - 0.5f;
            float p1 = p0 + (1.0f / 256.0f);
            p0 = fminf(fmaxf(p0, 0.0f), 127.0f);
            p1 = fminf(fmaxf(p1, 0.0f), 127.0f);
            int l0 = (int)p0, l1 = (int)p1;
            int h0 = min(l0 + 1, 127), h1 = min(l1 + 1, 127);
            float w0a = p0 - (float)l0, w1a = p1 - (float)l1;
            float a0 = amp_s[l0] * (1.0f - w0a) + amp_s[h0] * w0a;
            float a1 = amp_s[l1] * (1.0f - w1a) + amp_s[h1] * w1a;
            a0 = fminf(fmaxf(a0, 0.0f), 1.0f);
            a1 = fminf(fmaxf(a1, 0.0f), 1.0f);
            fo[A] = (v2){8.0f * y.x * a0, 8.0f * y.y * a1};
        }
    }
}

// ---------------------------------------------------------------------------
// Reduce: out[g][s] = sine (already in out) + sum_e filt[g*8+e][s].
// 36 MB read + 4 MB write; XCD swizzle matches fused kernel's writes.
// ---------------------------------------------------------------------------
__global__ __launch_bounds__(256) void reduce_kernel(
    const float* __restrict__ part, float* __restrict__ out)
{
    const int b = blockIdx.x;                         // 0..1023
    const int g = (b & 7) + 8 * ((b >> 3) & 3);       // group 0..31
    const int chunk = b >> 5;                         // 0..31
    const int s = (chunk << 10) + ((int)threadIdx.x << 2);

    float4 a = *(const float4*)(out + ((size_t)g << 15) + s);   // sine
#pragma unroll
    for (int e = 0; e < 8; e++) {
        const float4 f = *(const float4*)(part + ((size_t)(g * 8 + e) << 15) + s);
        a.x += f.x; a.y += f.y; a.z += f.z; a.w += f.w;
    }
    *(float4*)(out + ((size_t)g << 15) + s) = a;
}

extern "C" void kernel_launch(void* const* d_in, const int* in_sizes, int n_in,
                              void* d_out, int out_size, void* d_ws, size_t ws_size,
                              hipStream_t stream)
{
    (void)in_sizes; (void)n_in; (void)out_size; (void)ws_size;
    const float* packed = (const float*)d_in[0];
    const float* freqs  = (const float*)d_in[1];
    const float* noise  = (const float*)d_in[2];
    float* out = (float*)d_out;
    float* part = (float*)d_ws;      // 256 * 32768 * 4 B = 32 MB (filt partials)

    hipLaunchKernelGGL(fused_kernel, dim3(256), dim3(1024), 0, stream,
                       packed, freqs, noise, part, out);
    hipLaunchKernelGGL(reduce_kernel, dim3(1024), dim3(256), 0, stream,
                       part, out);
}

// Round 9
// 120.444 us; speedup vs baseline: 2.6087x; 2.6087x over previous
//
#include <hip/hip_runtime.h>
#include <math.h>

#ifndef M_PI
#define M_PI 3.14159265358979323846
#endif

#define NSAMP 32768
#define MHALF 16384
#define TWO_PI_F 6.2831853071795864f
#define PSTRIDE 1089   // plane stride in v2; 1089&15==1 spreads planes across bank pairs

typedef float v2 __attribute__((ext_vector_type(2)));

__device__ __forceinline__ double dsig(double x) { return 1.0 / (1.0 + exp(-x)); }

// ---------------------------------------------------------------------------
// Complex helpers on packed 2-float vectors
// ---------------------------------------------------------------------------
__device__ __forceinline__ v2 cmul(v2 a, v2 b) {
    return a.xx * b + (v2){-a.y, a.y} * b.yx;
}

template<int INV>
__device__ __forceinline__ void fft4(v2& x0, v2& x1, v2& x2, v2& x3) {
    v2 s02 = x0 + x2;
    v2 d02 = x0 - x2;
    v2 s13 = x1 + x3;
    v2 d13 = x1 - x3;
    v2 j13 = INV ? (v2){-d13.y, d13.x} : (v2){d13.y, -d13.x};
    x0 = s02 + s13;
    x2 = s02 - s13;
    x1 = d02 + j13;
    x3 = d02 - j13;
}

// After fft16, natural-order output index c lives in register V16(v,c).
#define V16(v, c) v[((((c) & 3) << 2) | ((c) >> 2))]

template<int INV>
__device__ __forceinline__ void fft16(v2 v[16]) {
    const float s = INV ? 1.0f : -1.0f;
#pragma unroll
    for (int b = 0; b < 4; b++) fft4<INV>(v[b], v[4 + b], v[8 + b], v[12 + b]);
    v[5]  = cmul(v[5],  (v2){0.9238795325f,  s * 0.3826834324f});
    v[9]  = cmul(v[9],  (v2){0.7071067812f,  s * 0.7071067812f});
    v[13] = cmul(v[13], (v2){0.3826834324f,  s * 0.9238795325f});
    v[6]  = cmul(v[6],  (v2){0.7071067812f,  s * 0.7071067812f});
    v[10] = cmul(v[10], (v2){0.0f,           s * 1.0f});
    v[14] = cmul(v[14], (v2){-0.7071067812f, s * 0.7071067812f});
    v[7]  = cmul(v[7],  (v2){0.3826834324f,  s * 0.9238795325f});
    v[11] = cmul(v[11], (v2){-0.7071067812f, s * 0.7071067812f});
    v[15] = cmul(v[15], (v2){-0.9238795325f, s * -0.3826834324f});
#pragma unroll
    for (int p = 0; p < 4; p++) fft4<INV>(v[4 * p], v[4 * p + 1], v[4 * p + 2], v[4 * p + 3]);
}

// spectral k (0..16383) -> LDS index.
__device__ __forceinline__ int zaddr(int k) {
    int p = k & 15, k2 = k >> 4;
    int s = 256 * (k2 & 3) + 16 * ((k2 >> 2) & 15) + (k2 >> 6);
    return p * PSTRIDE + s + (s >> 4);
}

// forward wave-local 1024-pt FFT on plane (lane l).
__device__ __forceinline__ void plane_fwd(v2* __restrict__ Zp, int l) {
    {
        float sn, cs;
        __sincosf(TWO_PI_F * (float)l * (1.f / 1024.f), &sn, &cs);
        v2 w1 = (v2){cs, -sn};
        const v2 jstep = (v2){0.9238795325f, -0.3826834324f}; // e^{-2pi i/16}
#pragma unroll
        for (int j = 0; j < 4; j++) {
            const int r = 64 * j + l;
            v2 u0 = Zp[r], u1 = Zp[256 + r], u2 = Zp[512 + r], u3 = Zp[768 + r];
            fft4<0>(u0, u1, u2, u3);
            v2 w2 = cmul(w1, w1);
            v2 w3 = cmul(w2, w1);
            Zp[r] = u0;
            Zp[256 + r] = cmul(u1, w1);
            Zp[512 + r] = cmul(u2, w2);
            Zp[768 + r] = cmul(u3, w3);
            w1 = cmul(w1, jstep);
        }
    }
    {
        const int k4 = l >> 4, c = l & 15;
        const int nbase = 256 * k4 + c;
        float sn, cs;
        __sincosf(TWO_PI_F * (float)c * (1.f / 256.f), &sn, &cs);
        const v2 wc = (v2){cs, -sn};
        v2 v[16];
#pragma unroll
        for (int b = 0; b < 16; b++) v[b] = Zp[nbase + 16 * b];
        fft16<0>(v);
        const int pbase = 272 * k4 + c;
        Zp[pbase] = V16(v, 0);
        v2 w = wc;
#pragma unroll
        for (int kb = 1; kb < 16; kb++) {
            Zp[pbase + 17 * kb] = cmul(V16(v, kb), w);
            w = cmul(w, wc);
        }
    }
    {
        const int pbase = 272 * (l >> 4) + 17 * (l & 15);
        v2 v[16];
#pragma unroll
        for (int c = 0; c < 16; c++) v[c] = Zp[pbase + c];
        fft16<0>(v);
#pragma unroll
        for (int kc = 0; kc < 16; kc++) Zp[pbase + kc] = V16(v, kc);
    }
}

// inverse wave-local 1024-pt FFT (mirror order, conjugate twiddles).
__device__ __forceinline__ void plane_inv(v2* __restrict__ Zp, int l) {
    {
        const int kb = l & 15;
        const int pbase = 272 * (l >> 4) + 17 * kb;
        float sn, cs;
        __sincosf(TWO_PI_F * (float)kb * (1.f / 256.f), &sn, &cs);
        const v2 wkb = (v2){cs, sn};
        v2 v[16];
#pragma unroll
        for (int kc = 0; kc < 16; kc++) v[kc] = Zp[pbase + kc];
        fft16<1>(v);
        Zp[pbase] = V16(v, 0);
        v2 w = wkb;
#pragma unroll
        for (int nc = 1; nc < 16; nc++) {
            Zp[pbase + nc] = cmul(V16(v, nc), w);
            w = cmul(w, wkb);
        }
    }
    {
        const int k4 = l >> 4, nc = l & 15;
        const int pbase = 272 * k4 + nc;
        float sni, csi;
        __sincosf(TWO_PI_F * (float)(nc * k4) * (1.f / 1024.f), &sni, &csi);
        v2 t = (v2){csi, sni};
        float sns, css;
        __sincosf(TWO_PI_F * (float)k4 * (1.f / 64.f), &sns, &css);
        const v2 st = (v2){css, sns};
        v2 v[16];
#pragma unroll
        for (int kb = 0; kb < 16; kb++) v[kb] = Zp[pbase + 17 * kb];
        fft16<1>(v);
#pragma unroll
        for (int nb = 0; nb < 16; nb++) {
            Zp[pbase + 17 * nb] = cmul(V16(v, nb), t);
            t = cmul(t, st);
        }
    }
#pragma unroll
    for (int j = 0; j < 4; j++) {
        const int r = 64 * j + l;
        const int rp = r + (r >> 4);
        v2 u0 = Zp[rp], u1 = Zp[272 + rp], u2 = Zp[544 + rp], u3 = Zp[816 + rp];
        fft4<1>(u0, u1, u2, u3);
        Zp[rp] = u0; Zp[272 + rp] = u1; Zp[544 + rp] = u2; Zp[816 + rp] = u3;
    }
}

__device__ __forceinline__ float hinterp64(const float* f, int j) {
    float pos = ((float)j + 0.5f) * (1.0f / 256.0f) - 0.5f;
    pos = fminf(fmaxf(pos, 0.0f), 63.0f);
    int lo = (int)pos;
    int hi = min(lo + 1, 63);
    float w = pos - (float)lo;
    return f[lo] * (1.0f - w) + f[hi] * w;
}

// ---------------------------------------------------------------------------
// Sine-synthesis chunk J, Chebyshev-recurrence version.
// step_h = (h+1)*step_1 exactly in Q0.64, so sin(phase_h) = sin((h+1)*theta)
// with theta the fundamental's phase: compute 1 sin + 1 cos per sample and
// chain s_{h+1} = 2cos*s_h - s_{h-1}.
// Immediate emission (no persistent accumulators -> no spill; rounds 3/7/8
// all proved any cross-phase register state spills at the 64-VGPR ceiling).
// ---------------------------------------------------------------------------
template<int J>
__device__ __forceinline__ void synth_chunk(
    int tid, const float* __restrict__ env_s,
    const unsigned long long* __restrict__ step_s, float* __restrict__ po)
{
    const int s0 = (tid << 2) + (J << 12);

    // env interpolation coefficients per sample (shared across harmonics)
    float c0v[4], c1v[4], c2v[4];
    float pos0 = ((float)s0 + 0.5f) * (1.0f / 256.0f) - 0.5f;
    pos0 = fminf(fmaxf(pos0, 0.0f), 127.0f);
    const int lo0 = (int)pos0;
#pragma unroll
    for (int k = 0; k < 4; k++) {
        float pos = ((float)(s0 + k) + 0.5f) * (1.0f / 256.0f) - 0.5f;
        pos = fminf(fmaxf(pos, 0.0f), 127.0f);
        int lo = (int)pos;
        float w = pos - (float)lo;
        if (lo == lo0) { c0v[k] = 1.0f - w; c1v[k] = w;        c2v[k] = 0.0f; }
        else           { c0v[k] = 0.0f;     c1v[k] = 1.0f - w; c2v[k] = w;    }
    }
    const int i1 = min(lo0 + 1, 127);
    float pos3 = ((float)(s0 + 3) + 0.5f) * (1.0f / 256.0f) - 0.5f;
    pos3 = fminf(fmaxf(pos3, 0.0f), 127.0f);
    const int i2 = min((int)pos3 + 1, 127);

    // per-harmonic envelope support points (compile-time indices after unroll)
    float v0a[8], v1a[8], v2a[8];
#pragma unroll
    for (int h = 0; h < 8; h++) {
        const float* er = env_s + (h << 7);
        v0a[h] = er[lo0]; v1a[h] = er[i1]; v2a[h] = er[i2];
    }

    // fundamental phase (revolutions) for sample s0, exact u64 seed
    const unsigned long long st1 = step_s[0];
    const float stf1 = (float)(unsigned)(st1 >> 32) * 0x1p-32f;
    const unsigned long long pp = st1 * (unsigned long long)(unsigned)(s0 + 1);
    float fr = (float)(unsigned)(pp >> 32) * 0x1p-32f;

    float out[4];
#pragma unroll
    for (int k = 0; k < 4; k++) {
        const float sn = __builtin_amdgcn_sinf(fr);
        const float cs = __builtin_amdgcn_cosf(fr);
        const float c2 = cs + cs;
        float s_prev = 0.0f, s_cur = sn;
        float a = 0.0f;
#pragma unroll
        for (int h = 0; h < 8; h++) {
            const float ev = fmaf(v0a[h], c0v[k], fmaf(v1a[h], c1v[k], v2a[h] * c2v[k]));
            a = fmaf(ev, s_cur, a);
            const float s_next = fmaf(c2, s_cur, -s_prev);
            s_prev = s_cur; s_cur = s_next;
        }
        out[k] = a;
        fr = __builtin_amdgcn_fractf(fr + stf1);
    }
    *(float4*)(po + s0) = make_float4(out[0], out[1], out[2], out[3]);
}

// ---------------------------------------------------------------------------
// Fused kernel (verified optimum, round 5: 46 us, VGPR 60, zero spill).
// blockIdx remapped so the 8 event-blocks of each group share an XCD
// (bid%8 == g%8 under round-robin dispatch) -> the reduce kernel, with the
// matching swizzle, reads partials from its own XCD's L2.
// amdgpu_waves_per_eu(4,4): LDS (145KB) caps at 1 block/CU = 4 waves/EU;
// pinning lets RA use the full budget instead of squeezing and spilling.
// ---------------------------------------------------------------------------
__global__ __launch_bounds__(1024)
__attribute__((amdgpu_waves_per_eu(4, 4)))
void fused_kernel(
    const float* __restrict__ packed, const float* __restrict__ freqs,
    const float* __restrict__ noise, float* __restrict__ part)
{
    __shared__ v2 Z[16 * PSTRIDE];   // 139,392 B
    __shared__ float fenv_s[64];
    __shared__ float amp_s[128];
    __shared__ float env_s[8 * 128];     // per-harmonic envelope (block-local)
    __shared__ unsigned long long step_s[8];

    const int bid = blockIdx.x;
    const int g = (bid & 7) + 8 * ((bid >> 3) & 3);   // group 0..31; bid%8 == g%8
    const int bb = g * 8 + (bid >> 5);                // event batch index 0..255
    const int tid = threadIdx.x;
    const int wv = tid >> 6, l = tid & 63;

    float* po_sine = part + ((size_t)(256 + bb) << 15);

    // ---- prep: entirely within wave 0 (no extra barriers; DS in-order per wave)
    if (tid < 64) {
        const float* pk = packed + bb * 464;
        double e0 = exp(dsig((double)pk[tid]));
        double e1 = exp(dsig((double)pk[tid + 64]));
        double num = e0 * (double)freqs[tid] + e1 * (double)freqs[tid + 64];
        double den = e0 + e1;
#pragma unroll
        for (int off = 32; off > 0; off >>= 1) {
            num += __shfl_down(num, off);
            den += __shfl_down(den, off);
        }
        num = __shfl(num, 0);
        den = __shfl(den, 0);

        float a0 = (float)(dsig((double)pk[256 + tid]) * 2.0 - 1.0);
        float a1 = (float)(dsig((double)pk[256 + 64 + tid]) * 2.0 - 1.0);
        amp_s[tid] = a0; amp_s[tid + 64] = a1;
        fenv_s[tid] = (float)dsig((double)pk[400 + tid]);

        if (tid < 8) {
            const double NYQ = 11025.0;
            const double MIN_F0 = 40.0 / NYQ;
            const double MAX_F0 = 3000.0 / NYQ;
            const double F0_SPAN = MAX_F0 - MIN_F0;
            double f0 = num / den;
            double F = f0 * NYQ;
            double G = MIN_F0 + F * F0_SPAN;
            double oscf = G * (double)(tid + 1);
            double r = oscf / NYQ * M_PI;
            double rv = r / (2.0 * M_PI);
            rv -= floor(rv);
            step_s[tid] = (unsigned long long)(rv * 18446744073709551616.0);

            // env recurrence in fp32 (reference is f32)
            float ha = (float)dsig((double)pk[384 + tid]);
            float hd = 0.9f + (float)dsig((double)pk[392 + tid]) * 0.1f;
            float cur = 0.0f;
            float* eo = env_s + (tid << 7);
            for (int fr = 0; fr < 128; fr++) {
                cur = fmaf(amp_s[fr], ha, cur);
                cur = fminf(fmaxf(cur, 0.0f), 1.0f);
                eo[fr] = cur;
                cur *= hd;
            }
        }
    }

    const v2* nz = (const v2*)(noise + (size_t)bb * NSAMP);

    // ---- forward outer: in-thread fft16 over n1 (stride 1024), scatter to planes
    {
        v2 v[16];
#pragma unroll
        for (int a = 0; a < 16; a++) {
            v2 t = nz[a * 1024 + tid];
            v[a] = t * 2.f - 1.f;
        }
        fft16<0>(v);
        float sn, cs;
        __sincosf(TWO_PI_F * (float)tid * (1.f / 16384.f), &sn, &cs);
        const v2 ws = (v2){cs, -sn};
        Z[tid] = V16(v, 0);
        v2 w = ws;
#pragma unroll
        for (int k1 = 1; k1 < 16; k1++) {
            Z[k1 * PSTRIDE + tid] = cmul(V16(v, k1), w);
            w = cmul(w, ws);
        }
    }
    __syncthreads();   // B1: prep + scatter visible

    synth_chunk<0>(tid, env_s, step_s, po_sine);
    synth_chunk<1>(tid, env_s, step_s, po_sine);

    plane_fwd(Z + wv * PSTRIDE, l);     // wave-local, no barriers

    synth_chunk<2>(tid, env_s, step_s, po_sine);
    synth_chunk<3>(tid, env_s, step_s, po_sine);
    __syncthreads();   // B2

    // ---- spectral combine (recurrence twiddles)
    const float invM = 1.0f / (float)MHALF;
    {
        float sn0, cs0;
        __sincosf((float)M_PI * (float)tid * (1.f / 16384.f), &sn0, &cs0);
        v2 t = (v2){cs0, sn0};
        const v2 tstep = (v2){0.98078528040323f, 0.19509032201613f}; // e^{+i pi/16}
        for (int k = tid; k <= 8192; k += 1024) {
            if (k == 0) {
                int i0 = zaddr(0);
                v2 Z0 = Z[i0];
                float Y0 = (Z0.x + Z0.y) * hinterp64(fenv_s, 0);
                float vv = Y0 * 0.5f * invM;
                Z[i0] = (v2){vv, vv};
            } else if (k == 8192) {
                int i8 = zaddr(8192);
                float s = hinterp64(fenv_s, 8192) * invM;
                Z[i8] = Z[i8] * s;
            } else {
                int ik = zaddr(k), imk = zaddr(16384 - k);
                v2 Zk = Z[ik], Zm = Z[imk];
                float Ex = 0.5f * (Zk.x + Zm.x);
                float Ey = 0.5f * (Zk.y - Zm.y);
                float Ox = 0.5f * (Zk.y + Zm.y);
                float Oy = -0.5f * (Zk.x - Zm.x);
                float cs = t.x, sn = t.y;
                float Xkx = Ex + cs * Ox + sn * Oy;
                float Xky = Ey + cs * Oy - sn * Ox;
                float Xmx = Ex - cs * Ox - sn * Oy;
                float Xmy = -Ey + cs * Oy - sn * Ox;
                float Hk = hinterp64(fenv_s, k);
                float Hm = hinterp64(fenv_s, 16384 - k);
                float Ykx = Xkx * Hk, Yky = Xky * Hk;
                float Ymx = Xmx * Hm, Ymy = Xmy * Hm;
                float Er = 0.5f * (Ykx + Ymx);
                float Ei = 0.5f * (Yky - Ymy);
                float Pr = 0.5f * (Ykx - Ymx);
                float Pi = 0.5f * (Yky + Ymy);
                float Oyx = Pr * cs - Pi * sn;
                float Oyy = Pr * sn + Pi * cs;
                Z[ik]  = (v2){(Er - Oyy) * invM, (Ei + Oyx) * invM};
                Z[imk] = (v2){(Er + Oyy) * invM, (-Ei + Oyx) * invM};
            }
            t = cmul(t, tstep);
        }
    }

    synth_chunk<4>(tid, env_s, step_s, po_sine);
    synth_chunk<5>(tid, env_s, step_s, po_sine);
    __syncthreads();   // B3

    plane_inv(Z + wv * PSTRIDE, l);     // wave-local, no barriers

    synth_chunk<6>(tid, env_s, step_s, po_sine);
    synth_chunk<7>(tid, env_s, step_s, po_sine);
    __syncthreads();   // B4

    // ---- inverse outer: gather across planes, twiddle, fft16, amp,
    //      store 8*filt*amp straight to global (coalesced v2)
    {
        const int tp = tid + (tid >> 4);
        v2 v[16];
#pragma unroll
        for (int k1 = 0; k1 < 16; k1++) v[k1] = Z[k1 * PSTRIDE + tp];
        float sn, cs;
        __sincosf(TWO_PI_F * (float)tid * (1.f / 16384.f), &sn, &cs);
        const v2 wg = (v2){cs, sn};
        v2 w = wg;
#pragma unroll
        for (int k1 = 1; k1 < 16; k1++) {
            v[k1] = cmul(v[k1], w);
            w = cmul(w, wg);
        }
        fft16<1>(v);

        v2* fo = (v2*)(part + ((size_t)bb << 15));
#pragma unroll
        for (int m = 0; m < 16; m++) {
            v2 y = V16(v, m);
            int A = m * 1024 + tid;
            int s0 = 2 * A;
            float p0 = ((float)s0 + 0.5f) * (1.0f / 256.0f) - 0.5f;
            float p1 = p0 + (1.0f / 256.0f);
            p0 = fminf(fmaxf(p0, 0.0f), 127.0f);
            p1 = fminf(fmaxf(p1, 0.0f), 127.0f);
            int l0 = (int)p0, l1 = (int)p1;
            int h0 = min(l0 + 1, 127), h1 = min(l1 + 1, 127);
            float w0a = p0 - (float)l0, w1a = p1 - (float)l1;
            float a0 = amp_s[l0] * (1.0f - w0a) + amp_s[h0] * w0a;
            float a1 = amp_s[l1] * (1.0f - w1a) + amp_s[h1] * w1a;
            a0 = fminf(fmaxf(a0, 0.0f), 1.0f);
            a1 = fminf(fmaxf(a1, 0.0f), 1.0f);
            fo[A] = (v2){8.0f * y.x * a0, 8.0f * y.y * a1};
        }
    }
}

// ---------------------------------------------------------------------------
// Reduce: out[g][s] = sum_e (filt_slice[g*8+e][s] + sine_slice[256+g*8+e][s]).
// Block swizzle matches the fused kernel's: block b has b%8 == g%8, so its
// reads target partials written on the SAME XCD (L2-hot).
// ---------------------------------------------------------------------------
__global__ __launch_bounds__(256) void reduce_kernel(
    const float* __restrict__ part, float* __restrict__ out)
{
    const int b = blockIdx.x;                         // 0..1023
    const int g = (b & 7) + 8 * ((b >> 3) & 3);       // group 0..31
    const int chunk = b >> 5;                         // 0..31
    const int s = (chunk << 10) + ((int)threadIdx.x << 2);

    float4 a = make_float4(0.f, 0.f, 0.f, 0.f);
#pragma unroll
    for (int e = 0; e < 8; e++) {
        const float4 f  = *(const float4*)(part + ((size_t)(g * 8 + e) << 15) + s);
        const float4 sn = *(const float4*)(part + ((size_t)(256 + g * 8 + e) << 15) + s);
        a.x += f.x + sn.x; a.y += f.y + sn.y;
        a.z += f.z + sn.z; a.w += f.w + sn.w;
    }
    *(float4*)(out + ((size_t)g << 15) + s) = a;
}

extern "C" void kernel_launch(void* const* d_in, const int* in_sizes, int n_in,
                              void* d_out, int out_size, void* d_ws, size_t ws_size,
                              hipStream_t stream)
{
    (void)in_sizes; (void)n_in; (void)out_size; (void)ws_size;
    const float* packed = (const float*)d_in[0];
    const float* freqs  = (const float*)d_in[1];
    const float* noise  = (const float*)d_in[2];
    float* out = (float*)d_out;
    float* part = (float*)d_ws;      // 512 * 32768 * 4 B = 64 MB

    hipLaunchKernelGGL(fused_kernel, dim3(256), dim3(1024), 0, stream,
                       packed, freqs, noise, part);
    hipLaunchKernelGGL(reduce_kernel, dim3(1024), dim3(256), 0, stream,
                       part, out);
}

// Round 10
// 116.784 us; speedup vs baseline: 2.6905x; 1.0313x over previous
//
#include <hip/hip_runtime.h>
#include <math.h>

#ifndef M_PI
#define M_PI 3.14159265358979323846
#endif

#define NSAMP 32768
#define MHALF 16384
#define TWO_PI_F 6.2831853071795864f
#define PSTRIDE 1089   // plane stride in v2; 1089&15==1 spreads planes across bank pairs

typedef float v2 __attribute__((ext_vector_type(2)));

__device__ __forceinline__ double dsig(double x) { return 1.0 / (1.0 + exp(-x)); }

// ---------------------------------------------------------------------------
// Complex helpers on packed 2-float vectors
// ---------------------------------------------------------------------------
__device__ __forceinline__ v2 cmul(v2 a, v2 b) {
    return a.xx * b + (v2){-a.y, a.y} * b.yx;
}

template<int INV>
__device__ __forceinline__ void fft4(v2& x0, v2& x1, v2& x2, v2& x3) {
    v2 s02 = x0 + x2;
    v2 d02 = x0 - x2;
    v2 s13 = x1 + x3;
    v2 d13 = x1 - x3;
    v2 j13 = INV ? (v2){-d13.y, d13.x} : (v2){d13.y, -d13.x};
    x0 = s02 + s13;
    x2 = s02 - s13;
    x1 = d02 + j13;
    x3 = d02 - j13;
}

// After fft16, natural-order output index c lives in register V16(v,c).
#define V16(v, c) v[((((c) & 3) << 2) | ((c) >> 2))]

template<int INV>
__device__ __forceinline__ void fft16(v2 v[16]) {
    const float s = INV ? 1.0f : -1.0f;
#pragma unroll
    for (int b = 0; b < 4; b++) fft4<INV>(v[b], v[4 + b], v[8 + b], v[12 + b]);
    v[5]  = cmul(v[5],  (v2){0.9238795325f,  s * 0.3826834324f});
    v[9]  = cmul(v[9],  (v2){0.7071067812f,  s * 0.7071067812f});
    v[13] = cmul(v[13], (v2){0.3826834324f,  s * 0.9238795325f});
    v[6]  = cmul(v[6],  (v2){0.7071067812f,  s * 0.7071067812f});
    v[10] = cmul(v[10], (v2){0.0f,           s * 1.0f});
    v[14] = cmul(v[14], (v2){-0.7071067812f, s * 0.7071067812f});
    v[7]  = cmul(v[7],  (v2){0.3826834324f,  s * 0.9238795325f});
    v[11] = cmul(v[11], (v2){-0.7071067812f, s * 0.7071067812f});
    v[15] = cmul(v[15], (v2){-0.9238795325f, s * -0.3826834324f});
#pragma unroll
    for (int p = 0; p < 4; p++) fft4<INV>(v[4 * p], v[4 * p + 1], v[4 * p + 2], v[4 * p + 3]);
}

// spectral k (0..16383) -> LDS index.
__device__ __forceinline__ int zaddr(int k) {
    int p = k & 15, k2 = k >> 4;
    int s = 256 * (k2 & 3) + 16 * ((k2 >> 2) & 15) + (k2 >> 6);
    return p * PSTRIDE + s + (s >> 4);
}

// forward wave-local 1024-pt FFT on plane (lane l).
__device__ __forceinline__ void plane_fwd(v2* __restrict__ Zp, int l) {
    {
        float sn, cs;
        __sincosf(TWO_PI_F * (float)l * (1.f / 1024.f), &sn, &cs);
        v2 w1 = (v2){cs, -sn};
        const v2 jstep = (v2){0.9238795325f, -0.3826834324f}; // e^{-2pi i/16}
#pragma unroll
        for (int j = 0; j < 4; j++) {
            const int r = 64 * j + l;
            v2 u0 = Zp[r], u1 = Zp[256 + r], u2 = Zp[512 + r], u3 = Zp[768 + r];
            fft4<0>(u0, u1, u2, u3);
            v2 w2 = cmul(w1, w1);
            v2 w3 = cmul(w2, w1);
            Zp[r] = u0;
            Zp[256 + r] = cmul(u1, w1);
            Zp[512 + r] = cmul(u2, w2);
            Zp[768 + r] = cmul(u3, w3);
            w1 = cmul(w1, jstep);
        }
    }
    {
        const int k4 = l >> 4, c = l & 15;
        const int nbase = 256 * k4 + c;
        float sn, cs;
        __sincosf(TWO_PI_F * (float)c * (1.f / 256.f), &sn, &cs);
        const v2 wc = (v2){cs, -sn};
        v2 v[16];
#pragma unroll
        for (int b = 0; b < 16; b++) v[b] = Zp[nbase + 16 * b];
        fft16<0>(v);
        const int pbase = 272 * k4 + c;
        Zp[pbase] = V16(v, 0);
        v2 w = wc;
#pragma unroll
        for (int kb = 1; kb < 16; kb++) {
            Zp[pbase + 17 * kb] = cmul(V16(v, kb), w);
            w = cmul(w, wc);
        }
    }
    {
        const int pbase = 272 * (l >> 4) + 17 * (l & 15);
        v2 v[16];
#pragma unroll
        for (int c = 0; c < 16; c++) v[c] = Zp[pbase + c];
        fft16<0>(v);
#pragma unroll
        for (int kc = 0; kc < 16; kc++) Zp[pbase + kc] = V16(v, kc);
    }
}

// inverse wave-local 1024-pt FFT (mirror order, conjugate twiddles).
__device__ __forceinline__ void plane_inv(v2* __restrict__ Zp, int l) {
    {
        const int kb = l & 15;
        const int pbase = 272 * (l >> 4) + 17 * kb;
        float sn, cs;
        __sincosf(TWO_PI_F * (float)kb * (1.f / 256.f), &sn, &cs);
        const v2 wkb = (v2){cs, sn};
        v2 v[16];
#pragma unroll
        for (int kc = 0; kc < 16; kc++) v[kc] = Zp[pbase + kc];
        fft16<1>(v);
        Zp[pbase] = V16(v, 0);
        v2 w = wkb;
#pragma unroll
        for (int nc = 1; nc < 16; nc++) {
            Zp[pbase + nc] = cmul(V16(v, nc), w);
            w = cmul(w, wkb);
        }
    }
    {
        const int k4 = l >> 4, nc = l & 15;
        const int pbase = 272 * k4 + nc;
        float sni, csi;
        __sincosf(TWO_PI_F * (float)(nc * k4) * (1.f / 1024.f), &sni, &csi);
        v2 t = (v2){csi, sni};
        float sns, css;
        __sincosf(TWO_PI_F * (float)k4 * (1.f / 64.f), &sns, &css);
        const v2 st = (v2){css, sns};
        v2 v[16];
#pragma unroll
        for (int kb = 0; kb < 16; kb++) v[kb] = Zp[pbase + 17 * kb];
        fft16<1>(v);
#pragma unroll
        for (int nb = 0; nb < 16; nb++) {
            Zp[pbase + 17 * nb] = cmul(V16(v, nb), t);
            t = cmul(t, st);
        }
    }
#pragma unroll
    for (int j = 0; j < 4; j++) {
        const int r = 64 * j + l;
        const int rp = r + (r >> 4);
        v2 u0 = Zp[rp], u1 = Zp[272 + rp], u2 = Zp[544 + rp], u3 = Zp[816 + rp];
        fft4<1>(u0, u1, u2, u3);
        Zp[rp] = u0; Zp[272 + rp] = u1; Zp[544 + rp] = u2; Zp[816 + rp] = u3;
    }
}

__device__ __forceinline__ float hinterp64(const float* f, int j) {
    float pos = ((float)j + 0.5f) * (1.0f / 256.0f) - 0.5f;
    pos = fminf(fmaxf(pos, 0.0f), 63.0f);
    int lo = (int)pos;
    int hi = min(lo + 1, 63);
    float w = pos - (float)lo;
    return f[lo] * (1.0f - w) + f[hi] * w;
}

// ---------------------------------------------------------------------------
// Sine-synthesis chunk J, Chebyshev-recurrence version (round-5 discipline:
// fully self-contained, immediate emission, no cross-phase register state).
// NOW writes into the COMBINED per-event slice part[bb]; the inverse-outer
// emit later read-modify-writes the same lines (L2-hot) adding the filt term.
// ---------------------------------------------------------------------------
template<int J>
__device__ __forceinline__ void synth_chunk(
    int tid, const float* __restrict__ env_s,
    const unsigned long long* __restrict__ step_s, float* __restrict__ po)
{
    const int s0 = (tid << 2) + (J << 12);

    // env interpolation coefficients per sample (shared across harmonics)
    float c0v[4], c1v[4], c2v[4];
    float pos0 = ((float)s0 + 0.5f) * (1.0f / 256.0f) - 0.5f;
    pos0 = fminf(fmaxf(pos0, 0.0f), 127.0f);
    const int lo0 = (int)pos0;
#pragma unroll
    for (int k = 0; k < 4; k++) {
        float pos = ((float)(s0 + k) + 0.5f) * (1.0f / 256.0f) - 0.5f;
        pos = fminf(fmaxf(pos, 0.0f), 127.0f);
        int lo = (int)pos;
        float w = pos - (float)lo;
        if (lo == lo0) { c0v[k] = 1.0f - w; c1v[k] = w;        c2v[k] = 0.0f; }
        else           { c0v[k] = 0.0f;     c1v[k] = 1.0f - w; c2v[k] = w;    }
    }
    const int i1 = min(lo0 + 1, 127);
    float pos3 = ((float)(s0 + 3) + 0.5f) * (1.0f / 256.0f) - 0.5f;
    pos3 = fminf(fmaxf(pos3, 0.0f), 127.0f);
    const int i2 = min((int)pos3 + 1, 127);

    // per-harmonic envelope support points (compile-time indices after unroll)
    float v0a[8], v1a[8], v2a[8];
#pragma unroll
    for (int h = 0; h < 8; h++) {
        const float* er = env_s + (h << 7);
        v0a[h] = er[lo0]; v1a[h] = er[i1]; v2a[h] = er[i2];
    }

    // fundamental phase (revolutions) for sample s0, exact u64 seed
    const unsigned long long st1 = step_s[0];
    const float stf1 = (float)(unsigned)(st1 >> 32) * 0x1p-32f;
    const unsigned long long pp = st1 * (unsigned long long)(unsigned)(s0 + 1);
    float fr = (float)(unsigned)(pp >> 32) * 0x1p-32f;

    float out[4];
#pragma unroll
    for (int k = 0; k < 4; k++) {
        const float sn = __builtin_amdgcn_sinf(fr);
        const float cs = __builtin_amdgcn_cosf(fr);
        const float c2 = cs + cs;
        float s_prev = 0.0f, s_cur = sn;
        float a = 0.0f;
#pragma unroll
        for (int h = 0; h < 8; h++) {
            const float ev = fmaf(v0a[h], c0v[k], fmaf(v1a[h], c1v[k], v2a[h] * c2v[k]));
            a = fmaf(ev, s_cur, a);
            const float s_next = fmaf(c2, s_cur, -s_prev);
            s_prev = s_cur; s_cur = s_next;
        }
        out[k] = a;
        fr = __builtin_amdgcn_fractf(fr + stf1);
    }
    *(float4*)(po + s0) = make_float4(out[0], out[1], out[2], out[3]);
}

// ---------------------------------------------------------------------------
// Fused kernel (round-5/9 verified structure, 46 us, VGPR 60, zero spill)
// + in-place sine/filt combine: synth chunks write sines into part[bb];
// the inverse-outer emit RMWs the same slice (sine + 8*amp*filt).
//   - visibility: B4 __syncthreads drains vmcnt for the whole block before
//     the emit reads other threads' sine writes (same block, same XCD L2).
//   - L2 budget: 32 blocks/XCD x 128 KB slice = 4 MB = L2 size, and no
//     intervening global traffic -> readback is L2-hot, and most sine lines
//     are overwritten before HBM eviction.
// Reduce then reads only the 32 MB of combined slices (was 68 MB).
// ---------------------------------------------------------------------------
__global__ __launch_bounds__(1024)
__attribute__((amdgpu_waves_per_eu(4, 4)))
void fused_kernel(
    const float* __restrict__ packed, const float* __restrict__ freqs,
    const float* __restrict__ noise, float* __restrict__ part)
{
    __shared__ v2 Z[16 * PSTRIDE];   // 139,392 B
    __shared__ float fenv_s[64];
    __shared__ float amp_s[128];
    __shared__ float env_s[8 * 128];     // per-harmonic envelope (block-local)
    __shared__ unsigned long long step_s[8];

    const int bid = blockIdx.x;
    const int g = (bid & 7) + 8 * ((bid >> 3) & 3);   // group 0..31; bid%8 == g%8
    const int bb = g * 8 + (bid >> 5);                // event batch index 0..255
    const int tid = threadIdx.x;
    const int wv = tid >> 6, l = tid & 63;

    float* po = part + ((size_t)bb << 15);   // combined sine+filt slice

    // ---- prep: entirely within wave 0 (no extra barriers; DS in-order per wave)
    if (tid < 64) {
        const float* pk = packed + bb * 464;
        double e0 = exp(dsig((double)pk[tid]));
        double e1 = exp(dsig((double)pk[tid + 64]));
        double num = e0 * (double)freqs[tid] + e1 * (double)freqs[tid + 64];
        double den = e0 + e1;
#pragma unroll
        for (int off = 32; off > 0; off >>= 1) {
            num += __shfl_down(num, off);
            den += __shfl_down(den, off);
        }
        num = __shfl(num, 0);
        den = __shfl(den, 0);

        float a0 = (float)(dsig((double)pk[256 + tid]) * 2.0 - 1.0);
        float a1 = (float)(dsig((double)pk[256 + 64 + tid]) * 2.0 - 1.0);
        amp_s[tid] = a0; amp_s[tid + 64] = a1;
        fenv_s[tid] = (float)dsig((double)pk[400 + tid]);

        if (tid < 8) {
            const double NYQ = 11025.0;
            const double MIN_F0 = 40.0 / NYQ;
            const double MAX_F0 = 3000.0 / NYQ;
            const double F0_SPAN = MAX_F0 - MIN_F0;
            double f0 = num / den;
            double F = f0 * NYQ;
            double G = MIN_F0 + F * F0_SPAN;
            double oscf = G * (double)(tid + 1);
            double r = oscf / NYQ * M_PI;
            double rv = r / (2.0 * M_PI);
            rv -= floor(rv);
            step_s[tid] = (unsigned long long)(rv * 18446744073709551616.0);

            // env recurrence in fp32 (reference is f32)
            float ha = (float)dsig((double)pk[384 + tid]);
            float hd = 0.9f + (float)dsig((double)pk[392 + tid]) * 0.1f;
            float cur = 0.0f;
            float* eo = env_s + (tid << 7);
            for (int fr = 0; fr < 128; fr++) {
                cur = fmaf(amp_s[fr], ha, cur);
                cur = fminf(fmaxf(cur, 0.0f), 1.0f);
                eo[fr] = cur;
                cur *= hd;
            }
        }
    }

    const v2* nz = (const v2*)(noise + (size_t)bb * NSAMP);

    // ---- forward outer: in-thread fft16 over n1 (stride 1024), scatter to planes
    {
        v2 v[16];
#pragma unroll
        for (int a = 0; a < 16; a++) {
            v2 t = nz[a * 1024 + tid];
            v[a] = t * 2.f - 1.f;
        }
        fft16<0>(v);
        float sn, cs;
        __sincosf(TWO_PI_F * (float)tid * (1.f / 16384.f), &sn, &cs);
        const v2 ws = (v2){cs, -sn};
        Z[tid] = V16(v, 0);
        v2 w = ws;
#pragma unroll
        for (int k1 = 1; k1 < 16; k1++) {
            Z[k1 * PSTRIDE + tid] = cmul(V16(v, k1), w);
            w = cmul(w, ws);
        }
    }
    __syncthreads();   // B1: prep + scatter visible

    synth_chunk<0>(tid, env_s, step_s, po);
    synth_chunk<1>(tid, env_s, step_s, po);

    plane_fwd(Z + wv * PSTRIDE, l);     // wave-local, no barriers

    synth_chunk<2>(tid, env_s, step_s, po);
    synth_chunk<3>(tid, env_s, step_s, po);
    __syncthreads();   // B2

    // ---- spectral combine (recurrence twiddles)
    const float invM = 1.0f / (float)MHALF;
    {
        float sn0, cs0;
        __sincosf((float)M_PI * (float)tid * (1.f / 16384.f), &sn0, &cs0);
        v2 t = (v2){cs0, sn0};
        const v2 tstep = (v2){0.98078528040323f, 0.19509032201613f}; // e^{+i pi/16}
        for (int k = tid; k <= 8192; k += 1024) {
            if (k == 0) {
                int i0 = zaddr(0);
                v2 Z0 = Z[i0];
                float Y0 = (Z0.x + Z0.y) * hinterp64(fenv_s, 0);
                float vv = Y0 * 0.5f * invM;
                Z[i0] = (v2){vv, vv};
            } else if (k == 8192) {
                int i8 = zaddr(8192);
                float s = hinterp64(fenv_s, 8192) * invM;
                Z[i8] = Z[i8] * s;
            } else {
                int ik = zaddr(k), imk = zaddr(16384 - k);
                v2 Zk = Z[ik], Zm = Z[imk];
                float Ex = 0.5f * (Zk.x + Zm.x);
                float Ey = 0.5f * (Zk.y - Zm.y);
                float Ox = 0.5f * (Zk.y + Zm.y);
                float Oy = -0.5f * (Zk.x - Zm.x);
                float cs = t.x, sn = t.y;
                float Xkx = Ex + cs * Ox + sn * Oy;
                float Xky = Ey + cs * Oy - sn * Ox;
                float Xmx = Ex - cs * Ox - sn * Oy;
                float Xmy = -Ey + cs * Oy - sn * Ox;
                float Hk = hinterp64(fenv_s, k);
                float Hm = hinterp64(fenv_s, 16384 - k);
                float Ykx = Xkx * Hk, Yky = Xky * Hk;
                float Ymx = Xmx * Hm, Ymy = Xmy * Hm;
                float Er = 0.5f * (Ykx + Ymx);
                float Ei = 0.5f * (Yky - Ymy);
                float Pr = 0.5f * (Ykx - Ymx);
                float Pi = 0.5f * (Yky + Ymy);
                float Oyx = Pr * cs - Pi * sn;
                float Oyy = Pr * sn + Pi * cs;
                Z[ik]  = (v2){(Er - Oyy) * invM, (Ei + Oyx) * invM};
                Z[imk] = (v2){(Er + Oyy) * invM, (-Ei + Oyx) * invM};
            }
            t = cmul(t, tstep);
        }
    }

    synth_chunk<4>(tid, env_s, step_s, po);
    synth_chunk<5>(tid, env_s, step_s, po);
    __syncthreads();   // B3

    plane_inv(Z + wv * PSTRIDE, l);     // wave-local, no barriers

    synth_chunk<6>(tid, env_s, step_s, po);
    synth_chunk<7>(tid, env_s, step_s, po);
    __syncthreads();   // B4: LDS ready AND all sine vmem writes drained

    // ---- inverse outer: gather across planes, twiddle, fft16, amp,
    //      RMW: slice = sine (readback, L2-hot) + 8*amp*filt
    {
        const int tp = tid + (tid >> 4);
        v2 v[16];
#pragma unroll
        for (int k1 = 0; k1 < 16; k1++) v[k1] = Z[k1 * PSTRIDE + tp];
        float sn, cs;
        __sincosf(TWO_PI_F * (float)tid * (1.f / 16384.f), &sn, &cs);
        const v2 wg = (v2){cs, sn};
        v2 w = wg;
#pragma unroll
        for (int k1 = 1; k1 < 16; k1++) {
            v[k1] = cmul(v[k1], w);
            w = cmul(w, wg);
        }
        fft16<1>(v);

        v2* fo = (v2*)po;
#pragma unroll
        for (int m = 0; m < 16; m++) {
            v2 y = V16(v, m);
            int A = m * 1024 + tid;
            int s0 = 2 * A;
            v2 sv = fo[A];                         // sine readback (own block's write)
            float p0 = ((float)s0 + 0.5f) * (1.0f / 256.0f) - 0.5f;
            float p1 = p0 + (1.0f / 256.0f);
            p0 = fminf(fmaxf(p0, 0.0f), 127.0f);
            p1 = fminf(fmaxf(p1, 0.0f), 127.0f);
            int l0 = (int)p0, l1 = (int)p1;
            int h0 = min(l0 + 1, 127), h1 = min(l1 + 1, 127);
            float w0a = p0 - (float)l0, w1a = p1 - (float)l1;
            float a0 = amp_s[l0] * (1.0f - w0a) + amp_s[h0] * w0a;
            float a1 = amp_s[l1] * (1.0f - w1a) + amp_s[h1] * w1a;
            a0 = fminf(fmaxf(a0, 0.0f), 1.0f);
            a1 = fminf(fmaxf(a1, 0.0f), 1.0f);
            fo[A] = (v2){sv.x + 8.0f * y.x * a0, sv.y + 8.0f * y.y * a1};
        }
    }
}

// ---------------------------------------------------------------------------
// Reduce: out[g][s] = sum_e combined[g*8+e][s]. 32 MB read (L2-mostly: 4 MB
// per XCD with matching swizzle) + 4 MB write.
// ---------------------------------------------------------------------------
__global__ __launch_bounds__(256) void reduce_kernel(
    const float* __restrict__ part, float* __restrict__ out)
{
    const int b = blockIdx.x;                         // 0..1023
    const int g = (b & 7) + 8 * ((b >> 3) & 3);       // group 0..31
    const int chunk = b >> 5;                         // 0..31
    const int s = (chunk << 10) + ((int)threadIdx.x << 2);

    float4 a = make_float4(0.f, 0.f, 0.f, 0.f);
#pragma unroll
    for (int e = 0; e < 8; e++) {
        const float4 f = *(const float4*)(part + ((size_t)(g * 8 + e) << 15) + s);
        a.x += f.x; a.y += f.y; a.z += f.z; a.w += f.w;
    }
    *(float4*)(out + ((size_t)g << 15) + s) = a;
}

extern "C" void kernel_launch(void* const* d_in, const int* in_sizes, int n_in,
                              void* d_out, int out_size, void* d_ws, size_t ws_size,
                              hipStream_t stream)
{
    (void)in_sizes; (void)n_in; (void)out_size; (void)ws_size;
    const float* packed = (const float*)d_in[0];
    const float* freqs  = (const float*)d_in[1];
    const float* noise  = (const float*)d_in[2];
    float* out = (float*)d_out;
    float* part = (float*)d_ws;      // 256 * 32768 * 4 B = 32 MB (combined slices)

    hipLaunchKernelGGL(fused_kernel, dim3(256), dim3(1024), 0, stream,
                       packed, freqs, noise, part);
    hipLaunchKernelGGL(reduce_kernel, dim3(1024), dim3(256), 0, stream,
                       part, out);
}